// Round 7
// baseline (141.262 us; speedup 1.0000x reference)
//
#include <hip/hip_runtime.h>

#define B_DIM 32
#define T_DIM 512
#define D_DIM 256
#define U_DIM 1024

typedef __bf16 bf16_t;
typedef bf16_t bf16x8 __attribute__((ext_vector_type(8)));
typedef float f32x4 __attribute__((ext_vector_type(4)));

#define RING 4
#define ROWP 20  // padded LDS row length (floats); measured 0 bank conflicts in R5/R6

__device__ __forceinline__ float ssign(float z) {
    return z * __builtin_amdgcn_rcpf(1.0f + __builtin_fabsf(z));
}

__device__ __forceinline__ int ldacq(int* p) {
    return __hip_atomic_load(p, __ATOMIC_ACQUIRE, __HIP_MEMORY_SCOPE_WORKGROUP);
}
__device__ __forceinline__ void strel(int* p, int v) {
    __hip_atomic_store(p, v, __ATOMIC_RELEASE, __HIP_MEMORY_SCOPE_WORKGROUP);
}

// Single-dispatch fused GEMM+scan with wave specialization.
// Block = 128 threads: wave0 = GEMM producer, wave1 = scan consumer.
// One block per (b, 64-u tile) -> grid (32,16) = 512 blocks, 2 blocks/CU.
// Producer: per 16-t chunk, load X f32 (ping-pong raw regs), cast bf16, 32 MFMAs
// (M=16,N=64,K=256, W pinned in 128 VGPRs), stash transposed into LDS ring slot,
// release flag. Consumer: acquire flag, ds_read next chunk early, 16 sequential
// softsign steps, 256B coalesced stores, release consumed-counter.
// XW never touches global memory; no workspace at all.
__global__ __launch_bounds__(128, 1) void fused3(
        const float* __restrict__ Xv, const float* __restrict__ A0,
        const float* __restrict__ b0, const float* __restrict__ As,
        const float* __restrict__ bs, const float* __restrict__ bd,
        const float* __restrict__ Xts, const float* __restrict__ Wd,
        float* __restrict__ out) {
    __shared__ float ring[RING][64 * ROWP];  // 20 KB
    __shared__ int prodflag[RING];
    __shared__ int consflag;
    __shared__ float xvs[D_DIM];

    const int tid = threadIdx.x;
    const int wave = tid >> 6;
    const int lane = tid & 63;
    const int b = blockIdx.x;       // linear%8 == b%8 -> all 16 u-tiles of b on one XCD
    const int u0 = blockIdx.y * 64;

    if (tid < RING) prodflag[tid] = 0;
    if (tid == RING) consflag = 0;
    __syncthreads();  // one-time init barrier; no barriers after this point

    if (wave == 0) {
        // ================= producer =================
        const int lm = lane & 15, q = lane >> 4;

        // W fragments straight from Wd f32 [k][u], cast bf16 (identical rounding to
        // the old transpose path). bW[n][kb][j] = W[kb*32+q*8+j][u0+n*16+lm].
        bf16x8 bW[4][8];
        #pragma unroll
        for (int n = 0; n < 4; ++n) {
            #pragma unroll
            for (int kb = 0; kb < 8; ++kb) {
                bf16x8 v;
                #pragma unroll
                for (int j = 0; j < 8; ++j)
                    v[j] = (bf16_t)Wd[(size_t)(kb * 32 + q * 8 + j) * U_DIM + u0 + n * 16 + lm];
                bW[n][kb] = v;
            }
        }

        const float* xrow = Xts + ((size_t)b * T_DIM + lm) * D_DIM + q * 8;

#define PLOAD(DST, CH)                                                               \
    {                                                                                \
        const float* xp_ = xrow + (size_t)(CH) * 16 * D_DIM;                         \
        _Pragma("unroll")                                                            \
        for (int kb = 0; kb < 8; ++kb) {                                             \
            DST[kb][0] = *(const f32x4*)(xp_ + kb * 32);                             \
            DST[kb][1] = *(const f32x4*)(xp_ + kb * 32 + 4);                         \
        }                                                                            \
    }

#define PCHUNK(RAW, C)                                                               \
    {                                                                                \
        bf16x8 aF[8];                                                                \
        _Pragma("unroll")                                                            \
        for (int kb = 0; kb < 8; ++kb) {                                             \
            bf16x8 v;                                                                \
            _Pragma("unroll")                                                        \
            for (int j = 0; j < 4; ++j) {                                            \
                v[j]     = (bf16_t)RAW[kb][0][j];                                    \
                v[4 + j] = (bf16_t)RAW[kb][1][j];                                    \
            }                                                                        \
            aF[kb] = v;                                                              \
        }                                                                            \
        f32x4 acc[4];                                                                \
        _Pragma("unroll")                                                            \
        for (int n = 0; n < 4; ++n) acc[n] = (f32x4){0.f, 0.f, 0.f, 0.f};            \
        _Pragma("unroll")                                                            \
        for (int kb = 0; kb < 8; ++kb) {                                             \
            _Pragma("unroll")                                                        \
            for (int n = 0; n < 4; ++n)                                              \
                acc[n] = __builtin_amdgcn_mfma_f32_16x16x32_bf16(aF[kb], bW[n][kb],  \
                                                                 acc[n], 0, 0, 0);   \
        }                                                                            \
        while (ldacq(&consflag) < (C) - (RING - 1)) __builtin_amdgcn_s_sleep(2);     \
        const int s_ = (C) & (RING - 1);                                             \
        _Pragma("unroll")                                                            \
        for (int n = 0; n < 4; ++n)                                                  \
            *(f32x4*)&ring[s_][(n * 16 + lm) * ROWP + q * 4] = acc[n];               \
        strel(&prodflag[s_], (C) + 1);                                               \
    }

        f32x4 rawA[8][2], rawB[8][2];
        PLOAD(rawA, 0);
        PLOAD(rawB, 1);
        for (int cc = 0; cc < T_DIM / 16; cc += 2) {
            PCHUNK(rawA, cc);
            if (cc + 2 < T_DIM / 16) PLOAD(rawA, cc + 2);
            PCHUNK(rawB, cc + 1);
            if (cc + 3 < T_DIM / 16) PLOAD(rawB, cc + 3);
        }
#undef PLOAD
#undef PCHUNK
    } else {
        // ================= consumer =================
        const int u = u0 + lane;

        ((float4*)xvs)[lane] = ((const float4*)(Xv + (size_t)b * D_DIM))[lane];
        float h0a = 0.f, dra = 0.f;
        #pragma unroll 8
        for (int d = 0; d < D_DIM; ++d) {
            const float x = xvs[d];
            h0a = fmaf(x, A0[(size_t)d * U_DIM + u], h0a);
            dra = fmaf(x, As[(size_t)d * U_DIM + u], dra);
        }
        float h = ssign(h0a + b0[u]);
        const float drive = dra + bs[u] + bd[u];

        float* po = out + (size_t)b * T_DIM * U_DIM + u;

        f32x4 cur[4], nxt[4];
        while (ldacq(&prodflag[0]) < 1) __builtin_amdgcn_s_sleep(2);
        #pragma unroll
        for (int i = 0; i < 4; ++i) cur[i] = *(const f32x4*)&ring[0][lane * ROWP + i * 4];

        for (int c = 0; c < T_DIM / 16; ++c) {
            if (c + 1 < T_DIM / 16) {
                const int s = (c + 1) & (RING - 1);
                while (ldacq(&prodflag[s]) < c + 2) __builtin_amdgcn_s_sleep(2);
                #pragma unroll
                for (int i = 0; i < 4; ++i) nxt[i] = *(const f32x4*)&ring[s][lane * ROWP + i * 4];
            }
            float xp[16];
            #pragma unroll
            for (int r = 0; r < 4; ++r) {
                xp[r]      = drive + cur[0][r];
                xp[4 + r]  = drive + cur[1][r];
                xp[8 + r]  = drive + cur[2][r];
                xp[12 + r] = drive + cur[3][r];
            }
            #pragma unroll
            for (int j = 0; j < 16; ++j) {
                h = ssign(h + xp[j]);
                po[(size_t)(c * 16 + j) * U_DIM] = h;
            }
            strel(&consflag, c + 1);
            #pragma unroll
            for (int i = 0; i < 4; ++i) cur[i] = nxt[i];
        }
    }
}

extern "C" void kernel_launch(void* const* d_in, const int* in_sizes, int n_in,
                              void* d_out, int out_size, void* d_ws, size_t ws_size,
                              hipStream_t stream) {
    const float* Xv  = (const float*)d_in[0];
    const float* Xts = (const float*)d_in[1];
    const float* A0  = (const float*)d_in[2];
    const float* b0  = (const float*)d_in[3];
    const float* As  = (const float*)d_in[4];
    const float* bs  = (const float*)d_in[5];
    const float* Wd  = (const float*)d_in[6];
    const float* bd  = (const float*)d_in[7];
    float* out = (float*)d_out;

    fused3<<<dim3(B_DIM, U_DIM / 64), dim3(128), 0, stream>>>(
        Xv, A0, b0, As, bs, bd, Xts, Wd, out);
}